// Round 10
// baseline (562.556 us; speedup 1.0000x reference)
//
#include <hip/hip_runtime.h>

#define NVOX 20000
#define MPTS 64
#define CIN  10
#define NM   (NVOX*MPTS)      // 1,280,000
#define EPSBN 1e-3f

// ws param layout (float offsets) — only 512 floats used
#define WS_SCALE0 0     // 64
#define WS_SHIFT0 64    // 64
#define WS_SCALE1 128   // 128
#define WS_SHIFT1 256   // 128

// d_out doubles as stream-ordered scratch for reduction partials.
#define NB0   1024      // stats0 blocks -> P0 partials [NB0][P0STR]
#define P0STR 72
#define NBS   10000     // STATS blocks: 2 voxels each -> partials [10000][256] = d_out exactly
#define NBF   20000     // FINAL blocks: 1 voxel each

typedef short bf16x8 __attribute__((ext_vector_type(8)));
typedef float f32x4  __attribute__((ext_vector_type(4)));
typedef unsigned int u32x4 __attribute__((ext_vector_type(4)));

__device__ __forceinline__ unsigned short f2bf(float f) {
    union { float f; unsigned u; } v; v.f = f;
    unsigned r = v.u + 0x7FFFu + ((v.u >> 16) & 1u);   // RNE to bf16
    return (unsigned short)(r >> 16);
}
// HW packed f32x2 -> bf16x2 (no builtin on gfx950)
__device__ __forceinline__ unsigned cvtpk(float lo, float hi) {
    unsigned d;
    asm("v_cvt_pk_bf16_f32 %0, %1, %2" : "=v"(d) : "v"(lo), "v"(hi));
    return d;
}
// packed u16 max: valid max for ReLU'd (non-negative) bf16 bit patterns
__device__ __forceinline__ unsigned pkmax(unsigned a, unsigned b) {
    unsigned d;
    asm("v_pk_max_u16 %0, %1, %2" : "=v"(d) : "v"(a), "v"(b));
    return d;
}

// x-moment pass: Sx (10) + Sxx (55 packed) via per-block partials, NO atomics.
__global__ __launch_bounds__(256) void k_stats0(const float* __restrict__ x,
                                                float* __restrict__ p0) {
    __shared__ float sm[4][P0STR];
    float sx[CIN];
    float sxx[55];
#pragma unroll
    for (int i = 0; i < CIN; i++) sx[i] = 0.f;
#pragma unroll
    for (int k = 0; k < 55; k++) sxx[k] = 0.f;

    const int t = threadIdx.x;
    const int tid = blockIdx.x * 256 + t;

    for (int g = tid; g < NM / 2; g += NB0 * 256) {
        const float4* xp = (const float4*)(x + (size_t)g * 20);
        float4 a = xp[0], b = xp[1], c = xp[2], d = xp[3], e = xp[4];
        float v0[CIN] = {a.x, a.y, a.z, a.w, b.x, b.y, b.z, b.w, c.x, c.y};
        float v1[CIN] = {c.z, c.w, d.x, d.y, d.z, d.w, e.x, e.y, e.z, e.w};
#pragma unroll
        for (int i = 0; i < CIN; i++) sx[i] += v0[i] + v1[i];
#pragma unroll
        for (int i = 0; i < CIN; i++)
#pragma unroll
            for (int j = 0; j <= i; j++)
                sxx[i * (i + 1) / 2 + j] += v0[i] * v0[j] + v1[i] * v1[j];
    }

    const int l = t & 63, w = t >> 6;
#pragma unroll
    for (int i = 0; i < CIN; i++) {
        float v = sx[i];
#pragma unroll
        for (int off = 32; off; off >>= 1) v += __shfl_xor(v, off, 64);
        if (l == 0) sm[w][i] = v;
    }
#pragma unroll
    for (int k = 0; k < 55; k++) {
        float v = sxx[k];
#pragma unroll
        for (int off = 32; off; off >>= 1) v += __shfl_xor(v, off, 64);
        if (l == 0) sm[w][10 + k] = v;
    }
    __syncthreads();
    if (t < 65)
        p0[blockIdx.x * P0STR + t] = sm[0][t] + sm[1][t] + sm[2][t] + sm[3][t];
}

__global__ void k_finalize0(const float* __restrict__ p0, float* __restrict__ ws,
                            const float* __restrict__ w0,
                            const float* __restrict__ gamma0, const float* __restrict__ beta0) {
    __shared__ float s[P0STR];
    const int t = threadIdx.x;
    if (t < 65) {
        float acc = 0.f;
#pragma unroll 8
        for (int r = 0; r < NB0; r++) acc += p0[r * P0STR + t];
        s[t] = acc;
    }
    __syncthreads();
    if (t < 64) {
        float w[CIN];
#pragma unroll
        for (int i = 0; i < CIN; i++) w[i] = w0[t * CIN + i];
        float m = 0.f;
#pragma unroll
        for (int i = 0; i < CIN; i++) m += w[i] * s[i];
        m *= (1.f / NM);
        float q = 0.f;
#pragma unroll
        for (int i = 0; i < CIN; i++)
#pragma unroll
            for (int j = 0; j <= i; j++)
                q += ((i == j) ? 1.f : 2.f) * w[i] * w[j] * s[10 + i * (i + 1) / 2 + j];
        q *= (1.f / NM);
        float var = q - m * m;
        float scale = gamma0[t] * rsqrtf(var + EPSBN);
        ws[WS_SCALE0 + t] = scale;
        ws[WS_SHIFT0 + t] = beta0[t] - m * scale;
    }
}

__global__ void k_finalize1(const float* __restrict__ p1, float* __restrict__ ws,
                            const float* __restrict__ gamma1, const float* __restrict__ beta1) {
    __shared__ float sm[2][4];
    const int c = blockIdx.x;
    const int t = threadIdx.x, l = t & 63, w = t >> 6;
    float s = 0.f, qq = 0.f;
    for (int r = t; r < NBS; r += 256) {
        s  += p1[(size_t)r * 256 + c];
        qq += p1[(size_t)r * 256 + 128 + c];
    }
#pragma unroll
    for (int off = 32; off; off >>= 1) { s += __shfl_xor(s, off, 64); qq += __shfl_xor(qq, off, 64); }
    if (l == 0) { sm[0][w] = s; sm[1][w] = qq; }
    __syncthreads();
    if (t == 0) {
        float S = sm[0][0] + sm[0][1] + sm[0][2] + sm[0][3];
        float Q = sm[1][0] + sm[1][1] + sm[1][2] + sm[1][3];
        float m = S * (1.f / NM);
        float var = Q * (1.f / NM) - m * m;
        float scale = gamma1[c] * rsqrtf(var + EPSBN);
        ws[WS_SCALE1 + c] = scale;
        ws[WS_SHIFT1 + c] = beta1[c] - m * scale;
    }
}

// Single-shot voxel blocks: block-level TLP replaces the software pipeline.
// FINAL: 20000 blocks x 1 voxel (1 __syncthreads per block); STATS: 10000 blocks x
// 2 sequential voxels (extra WAR sync), partials [10000][256] == d_out size exactly.
// Proven R5 layout: zB [p][ch] stride 72 shorts (144 B = 9x16B slots -> natural
// per-row slot rotation, conflict-free per 8-lane beat). zB writes + AGG readback are
// wave-private (in-order DS per wave); cross-wave bz/gp reads happen after the sync.
// BN1 folded: wfrag pre-scaled by sc1 (FINAL), sh1 injected as dacc C-init (exact math,
// verified R9).
template <bool STATS>
__global__ __launch_bounds__(256) void k_pass(const float* __restrict__ x,
                                              const float* __restrict__ w0,
                                              const float* __restrict__ w1,
                                              const float* __restrict__ ws,
                                              float* __restrict__ pout) {
    __shared__ unsigned short zB[MPTS * 72];   // 9216 B  [p][ch]
    __shared__ unsigned short aggP[4 * 64];    // 512 B
    __shared__ float pbuf[256];                // 1024 B (STATS staging)

    const int t  = threadIdx.x;
    const int l  = t & 63;
    const int w  = t >> 6;
    const int lr = l & 15;
    const int lg = l >> 4;
    const int prow = 16 * w + lr;              // this lane's point row (produce)

    // W0 fragments, BN0 folded: A rows ch = 16mi+lr, k = 8lg+j (k10 = shift, rest 0)
    bf16x8 w0f[4];
#pragma unroll
    for (int mi = 0; mi < 4; mi++) {
        int ch = 16 * mi + lr;
        float sc = ws[WS_SCALE0 + ch], sh = ws[WS_SHIFT0 + ch];
        bf16x8 f;
#pragma unroll
        for (int j = 0; j < 8; j++) {
            int k = 8 * lg + j;
            float v = (k < CIN) ? sc * w0[ch * CIN + k] : (k == CIN ? sh : 0.f);
            f[j] = (short)f2bf(v);
        }
        w0f[mi] = f;
    }

    // W1 fragments: B cols o = 32w+16njl+lr, k = 32ks+8lg+j.
    // FINAL: rows pre-scaled by sc1[o]; shift goes into the dacc init.
    float sh1[2];
    bf16x8 wfrag[2][4];
#pragma unroll
    for (int njl = 0; njl < 2; njl++) {
        int col = 32 * w + 16 * njl + lr;
        float scl = 1.f;
        if constexpr (!STATS) {
            scl = ws[WS_SCALE1 + col];
            sh1[njl] = ws[WS_SHIFT1 + col];
        } else {
            sh1[njl] = 0.f;
        }
        const float* wrow = w1 + col * 128;
#pragma unroll
        for (int ks = 0; ks < 4; ks++) {
            float4 a = *(const float4*)(wrow + 32 * ks + 8 * lg);
            float4 b = *(const float4*)(wrow + 32 * ks + 8 * lg + 4);
            bf16x8 f;
            f[0] = (short)f2bf(scl * a.x); f[1] = (short)f2bf(scl * a.y);
            f[2] = (short)f2bf(scl * a.z); f[3] = (short)f2bf(scl * a.w);
            f[4] = (short)f2bf(scl * b.x); f[5] = (short)f2bf(scl * b.y);
            f[6] = (short)f2bf(scl * b.z); f[7] = (short)f2bf(scl * b.w);
            wfrag[njl][ks] = f;
        }
    }

    float as_[2] = {0.f, 0.f}, aq[2] = {0.f, 0.f};

    float2 pfA, pfB, pfC, pfD;
    auto PF = [&](int n) {
        const float* xr = x + (size_t)n * 640 + prow * CIN;
        if (lg == 0) {
            pfA = *(const float2*)(xr + 0); pfB = *(const float2*)(xr + 2);
            pfC = *(const float2*)(xr + 4); pfD = *(const float2*)(xr + 6);
        } else if (lg == 1) {
            pfA = *(const float2*)(xr + 8);
        }
    };
    auto MKBX = [&]() -> bf16x8 {
        u32x4 u = {0u, 0u, 0u, 0u};
        if (lg == 0) {
            u[0] = cvtpk(pfA.x, pfA.y); u[1] = cvtpk(pfB.x, pfB.y);
            u[2] = cvtpk(pfC.x, pfC.y); u[3] = cvtpk(pfD.x, pfD.y);
        } else if (lg == 1) {
            u[0] = cvtpk(pfA.x, pfA.y);
            u[1] = 0x00003F80u;       // k10 = 1.0 (shift lane), k11 = 0
        }
        return __builtin_bit_cast(bf16x8, u);
    };

    const int NV = STATS ? 2 : 1;
    PF(STATS ? blockIdx.x * 2 : blockIdx.x);

    for (int v = 0; v < NV; v++) {
        const int n = STATS ? (blockIdx.x * 2 + v) : blockIdx.x;

        bf16x8 bx = MKBX();
        if (STATS && v == 0) PF(blockIdx.x * 2 + 1);   // hide next voxel's x latency

        // ---- PRODUCE: L0 (4 MFMA + ReLU/pack + wave-private zB writes) + AGG ----
#pragma unroll
        for (int mi = 0; mi < 4; mi++) {
            f32x4 zz = {0.f, 0.f, 0.f, 0.f};
            f32x4 a0 = __builtin_amdgcn_mfma_f32_16x16x32_bf16(w0f[mi], bx, zz, 0, 0, 0);
            uint2 dd = { cvtpk(fmaxf(a0[0], 0.f), fmaxf(a0[1], 0.f)),
                         cvtpk(fmaxf(a0[2], 0.f), fmaxf(a0[3], 0.f)) };
            *(uint2*)&zB[prow * 72 + 16 * mi + 4 * lg] = dd;  // ch 16mi+4lg..+3
        }
        {
            int cs = l & 7;
            int pa = 16 * w + 2 * (l >> 3);
            u32x4 ra = *(const u32x4*)&zB[pa * 72 + cs * 8];
            u32x4 rb = *(const u32x4*)&zB[(pa + 1) * 72 + cs * 8];
            u32x4 m;
#pragma unroll
            for (int k2 = 0; k2 < 4; k2++) m[k2] = pkmax(ra[k2], rb[k2]);
#pragma unroll
            for (int off = 8; off <= 32; off <<= 1)
#pragma unroll
                for (int k2 = 0; k2 < 4; k2++) m[k2] = pkmax(m[k2], __shfl_xor(m[k2], off));
            if (l < 8) *(u32x4*)&aggP[w * 64 + l * 8] = m;
        }

        __syncthreads();   // zB + aggP globally visible

        // ---- consume-LOADS ----
        bf16x8 bz[4][2];
#pragma unroll
        for (int pj = 0; pj < 4; pj++)
#pragma unroll
            for (int ks = 0; ks < 2; ks++)
                bz[pj][ks] = *(const bf16x8*)&zB[(16 * pj + lr) * 72 + (4 * ks + lg) * 8];
        u32x4 gp[2][4];
#pragma unroll
        for (int ks = 0; ks < 2; ks++) {
            int sl = (4 * ks + lg) * 8;
#pragma unroll
            for (int wv = 0; wv < 4; wv++)
                gp[ks][wv] = *(const u32x4*)&aggP[wv * 64 + sl];
        }

        if (STATS && v + 1 < NV) __syncthreads();   // WAR: loads drained before next produce

        // ---- consume-COMPUTE ----
        bf16x8 gf[2];
#pragma unroll
        for (int ks = 0; ks < 2; ks++) {
            u32x4 g = gp[ks][0];
#pragma unroll
            for (int wv = 1; wv < 4; wv++)
#pragma unroll
                for (int k2 = 0; k2 < 4; k2++) g[k2] = pkmax(g[k2], gp[ks][wv][k2]);
            gf[ks] = __builtin_bit_cast(bf16x8, g);
        }
        f32x4 dacc[2];
#pragma unroll
        for (int njl = 0; njl < 2; njl++) {
            f32x4 zz = {sh1[njl], sh1[njl], sh1[njl], sh1[njl]};
            zz = __builtin_amdgcn_mfma_f32_16x16x32_bf16(gf[0], wfrag[njl][2], zz, 0, 0, 0);
            dacc[njl] = __builtin_amdgcn_mfma_f32_16x16x32_bf16(gf[1], wfrag[njl][3], zz, 0, 0, 0);
        }
#pragma unroll
        for (int njl = 0; njl < 2; njl++) {
            float vm = 0.f;
#pragma unroll
            for (int mi = 0; mi < 4; mi++) {
                f32x4 acc = dacc[njl];
                acc = __builtin_amdgcn_mfma_f32_16x16x32_bf16(bz[mi][0], wfrag[njl][0], acc, 0, 0, 0);
                acc = __builtin_amdgcn_mfma_f32_16x16x32_bf16(bz[mi][1], wfrag[njl][1], acc, 0, 0, 0);
                if (STATS) {
#pragma unroll
                    for (int r = 0; r < 4; r++) { as_[njl] += acc[r]; aq[njl] += acc[r] * acc[r]; }
                } else {
#pragma unroll
                    for (int r = 0; r < 4; r++) vm = fmaxf(vm, fmaxf(acc[r], 0.f));
                }
            }
            if (!STATS) {
                vm = fmaxf(vm, __shfl_xor(vm, 16));
                vm = fmaxf(vm, __shfl_xor(vm, 32));
                if (l < 16) pout[(size_t)n * 128 + 32 * w + 16 * njl + l] = vm;
            }
        }
    }

    if (STATS) {
        // disjoint cols across waves -> single staging array, one coalesced store
#pragma unroll
        for (int njl = 0; njl < 2; njl++) {
            float s = as_[njl];
            s += __shfl_xor(s, 16); s += __shfl_xor(s, 32);
            float qq = aq[njl];
            qq += __shfl_xor(qq, 16); qq += __shfl_xor(qq, 32);
            if (l < 16) {
                int col = 32 * w + 16 * njl + l;
                pbuf[col] = s;
                pbuf[128 + col] = qq;
            }
        }
        __syncthreads();
        pout[(size_t)blockIdx.x * 256 + t] = pbuf[t];
    }
}

extern "C" void kernel_launch(void* const* d_in, const int* in_sizes, int n_in,
                              void* d_out, int out_size, void* d_ws, size_t ws_size,
                              hipStream_t stream) {
    (void)in_sizes; (void)n_in; (void)out_size; (void)ws_size;
    const float* x      = (const float*)d_in[0];
    const float* W0     = (const float*)d_in[1];
    const float* gamma0 = (const float*)d_in[2];
    const float* beta0  = (const float*)d_in[3];
    const float* W1     = (const float*)d_in[4];
    const float* gamma1 = (const float*)d_in[5];
    const float* beta1  = (const float*)d_in[6];
    float* out = (float*)d_out;
    float* ws  = (float*)d_ws;

    k_stats0<<<NB0, 256, 0, stream>>>(x, out);                       // partials -> out
    k_finalize0<<<1, 256, 0, stream>>>(out, ws, W0, gamma0, beta0);
    k_pass<true><<<NBS, 256, 0, stream>>>(x, W0, W1, ws, out);       // partials -> out
    k_finalize1<<<128, 256, 0, stream>>>(out, ws, gamma1, beta1);
    k_pass<false><<<NBF, 256, 0, stream>>>(x, W0, W1, ws, out);      // final output
}

// Round 11
// 321.923 us; speedup vs baseline: 1.7475x; 1.7475x over previous
//
#include <hip/hip_runtime.h>

#define NVOX 20000
#define MPTS 64
#define CIN  10
#define NM   (NVOX*MPTS)      // 1,280,000
#define EPSBN 1e-3f

// ws param layout (float offsets) — only 512 floats used
#define WS_SCALE0 0     // 64
#define WS_SHIFT0 64    // 64
#define WS_SCALE1 128   // 128
#define WS_SHIFT1 256   // 128

// d_out doubles as stream-ordered scratch for reduction partials.
#define NB0   1024      // stats0 blocks -> P0 partials [NB0][P0STR]
#define P0STR 72
#define NBP   2500      // k_pass blocks; NITER voxels each, exact
#define NITER 8

typedef short bf16x8 __attribute__((ext_vector_type(8)));
typedef float f32x4  __attribute__((ext_vector_type(4)));
typedef unsigned int u32x4 __attribute__((ext_vector_type(4)));

__device__ __forceinline__ unsigned short f2bf(float f) {
    union { float f; unsigned u; } v; v.f = f;
    unsigned r = v.u + 0x7FFFu + ((v.u >> 16) & 1u);   // RNE to bf16
    return (unsigned short)(r >> 16);
}
// HW packed f32x2 -> bf16x2 (no builtin on gfx950)
__device__ __forceinline__ unsigned cvtpk(float lo, float hi) {
    unsigned d;
    asm("v_cvt_pk_bf16_f32 %0, %1, %2" : "=v"(d) : "v"(lo), "v"(hi));
    return d;
}
// packed u16 max: valid for NON-NEGATIVE bf16 patterns (post-ReLU agg)
__device__ __forceinline__ unsigned pkmax_u(unsigned a, unsigned b) {
    unsigned d;
    asm("v_pk_max_u16 %0, %1, %2" : "=v"(d) : "v"(a), "v"(b));
    return d;
}
// packed SIGNED i16 max vs 0 == ReLU on packed bf16 (neg bf16 -> neg i16 -> clamped)
__device__ __forceinline__ unsigned pkrelu(unsigned a) {
    unsigned d, z = 0;
    asm("v_pk_max_i16 %0, %1, %2" : "=v"(d) : "v"(a), "v"(z));
    return d;
}

// x-moment pass: Sx (10) + Sxx (55 packed) via per-block partials, NO atomics.
__global__ __launch_bounds__(256) void k_stats0(const float* __restrict__ x,
                                                float* __restrict__ p0) {
    __shared__ float sm[4][P0STR];
    float sx[CIN];
    float sxx[55];
#pragma unroll
    for (int i = 0; i < CIN; i++) sx[i] = 0.f;
#pragma unroll
    for (int k = 0; k < 55; k++) sxx[k] = 0.f;

    const int t = threadIdx.x;
    const int tid = blockIdx.x * 256 + t;

    for (int g = tid; g < NM / 2; g += NB0 * 256) {
        const float4* xp = (const float4*)(x + (size_t)g * 20);
        float4 a = xp[0], b = xp[1], c = xp[2], d = xp[3], e = xp[4];
        float v0[CIN] = {a.x, a.y, a.z, a.w, b.x, b.y, b.z, b.w, c.x, c.y};
        float v1[CIN] = {c.z, c.w, d.x, d.y, d.z, d.w, e.x, e.y, e.z, e.w};
#pragma unroll
        for (int i = 0; i < CIN; i++) sx[i] += v0[i] + v1[i];
#pragma unroll
        for (int i = 0; i < CIN; i++)
#pragma unroll
            for (int j = 0; j <= i; j++)
                sxx[i * (i + 1) / 2 + j] += v0[i] * v0[j] + v1[i] * v1[j];
    }

    const int l = t & 63, w = t >> 6;
#pragma unroll
    for (int i = 0; i < CIN; i++) {
        float v = sx[i];
#pragma unroll
        for (int off = 32; off; off >>= 1) v += __shfl_xor(v, off, 64);
        if (l == 0) sm[w][i] = v;
    }
#pragma unroll
    for (int k = 0; k < 55; k++) {
        float v = sxx[k];
#pragma unroll
        for (int off = 32; off; off >>= 1) v += __shfl_xor(v, off, 64);
        if (l == 0) sm[w][10 + k] = v;
    }
    __syncthreads();
    if (t < 65)
        p0[blockIdx.x * P0STR + t] = sm[0][t] + sm[1][t] + sm[2][t] + sm[3][t];
}

__global__ void k_finalize0(const float* __restrict__ p0, float* __restrict__ ws,
                            const float* __restrict__ w0,
                            const float* __restrict__ gamma0, const float* __restrict__ beta0) {
    __shared__ float s[P0STR];
    const int t = threadIdx.x;
    if (t < 65) {
        float acc = 0.f;
#pragma unroll 8
        for (int r = 0; r < NB0; r++) acc += p0[r * P0STR + t];
        s[t] = acc;
    }
    __syncthreads();
    if (t < 64) {
        float w[CIN];
#pragma unroll
        for (int i = 0; i < CIN; i++) w[i] = w0[t * CIN + i];
        float m = 0.f;
#pragma unroll
        for (int i = 0; i < CIN; i++) m += w[i] * s[i];
        m *= (1.f / NM);
        float q = 0.f;
#pragma unroll
        for (int i = 0; i < CIN; i++)
#pragma unroll
            for (int j = 0; j <= i; j++)
                q += ((i == j) ? 1.f : 2.f) * w[i] * w[j] * s[10 + i * (i + 1) / 2 + j];
        q *= (1.f / NM);
        float var = q - m * m;
        float scale = gamma0[t] * rsqrtf(var + EPSBN);
        ws[WS_SCALE0 + t] = scale;
        ws[WS_SHIFT0 + t] = beta0[t] - m * scale;
    }
}

__global__ void k_finalize1(const float* __restrict__ p1, float* __restrict__ ws,
                            const float* __restrict__ gamma1, const float* __restrict__ beta1) {
    __shared__ float sm[2][4];
    const int c = blockIdx.x;
    const int t = threadIdx.x, l = t & 63, w = t >> 6;
    float s = 0.f, qq = 0.f;
    for (int r = t; r < NBP; r += 256) {
        s  += p1[(size_t)r * 256 + c];
        qq += p1[(size_t)r * 256 + 128 + c];
    }
#pragma unroll
    for (int off = 32; off; off >>= 1) { s += __shfl_xor(s, off, 64); qq += __shfl_xor(qq, off, 64); }
    if (l == 0) { sm[0][w] = s; sm[1][w] = qq; }
    __syncthreads();
    if (t == 0) {
        float S = sm[0][0] + sm[0][1] + sm[0][2] + sm[0][3];
        float Q = sm[1][0] + sm[1][1] + sm[1][2] + sm[1][3];
        float m = S * (1.f / NM);
        float var = Q * (1.f / NM) - m * m;
        float scale = gamma1[c] * rsqrtf(var + EPSBN);
        ws[WS_SCALE1 + c] = scale;
        ws[WS_SHIFT1 + c] = beta1[c] - m * scale;
    }
}

// ZERO-LDS / ZERO-BARRIER k_pass. Each wave processes FULL voxels independently:
//   L0 for all 64 points (16 MFMA, 4x replicated across waves — MFMA pipe is idle anyway),
//   in-register repack: cvtpk pairs of L0's D[ch][p] output ARE valid L1 A-fragments under
//   the K-permutation kmap(lg,j) = 32ks + 16(j>>2) + 4lg + (j&3) (lane-dependent channel
//   order absorbed into the wfrag gather: two float4s at wrow+32ks+4lg and +16+4lg).
//   ReLU via packed i16 max vs 0; agg via pkmax over pj + 4-stage shfl_xor butterfly
//   (lands exactly in gfrag layout). Wave w consumes o-cols 32w..32w+31 (wfrag 32 VGPR).
// No inter-wave communication of any kind -> latency hidden by wave TLP, no lockstep.
// BN0 folded into w0f; BN1 folded into wfrag scale + dacc C-init (verified R9).
template <bool STATS>
__global__ __launch_bounds__(256) void k_pass(const float* __restrict__ x,
                                              const float* __restrict__ w0,
                                              const float* __restrict__ w1,
                                              const float* __restrict__ ws,
                                              float* __restrict__ pout) {
    const int t  = threadIdx.x;
    const int l  = t & 63;
    const int w  = t >> 6;
    const int lr = l & 15;
    const int lg = l >> 4;

    // W0 fragments, BN0 folded: A rows ch = 16mi+lr, k = 8lg+j (k10 = shift, rest 0)
    bf16x8 w0f[4];
#pragma unroll
    for (int mi = 0; mi < 4; mi++) {
        int ch = 16 * mi + lr;
        float sc = ws[WS_SCALE0 + ch], sh = ws[WS_SHIFT0 + ch];
        bf16x8 f;
#pragma unroll
        for (int j = 0; j < 8; j++) {
            int k = 8 * lg + j;
            float v = (k < CIN) ? sc * w0[ch * CIN + k] : (k == CIN ? sh : 0.f);
            f[j] = (short)f2bf(v);
        }
        w0f[mi] = f;
    }

    // W1 fragments under kmap: slot j of lane (lr,lg), chunk ks holds
    // W1[col][32ks + 16(j>>2) + 4lg + (j&3)]  -> two aligned float4 gathers.
    // ks 0,1 = z-part (k 0..63); ks 2,3 = rep-part (k 64..127): base 32ks covers both.
    float sh1[2];
    bf16x8 wfrag[2][4];
#pragma unroll
    for (int njl = 0; njl < 2; njl++) {
        int col = 32 * w + 16 * njl + lr;
        float scl = 1.f;
        if constexpr (!STATS) {
            scl = ws[WS_SCALE1 + col];
            sh1[njl] = ws[WS_SHIFT1 + col];
        } else {
            sh1[njl] = 0.f;
        }
        const float* wrow = w1 + col * 128;
#pragma unroll
        for (int ks = 0; ks < 4; ks++) {
            float4 a = *(const float4*)(wrow + 32 * ks + 4 * lg);
            float4 b = *(const float4*)(wrow + 32 * ks + 16 + 4 * lg);
            bf16x8 f;
            f[0] = (short)f2bf(scl * a.x); f[1] = (short)f2bf(scl * a.y);
            f[2] = (short)f2bf(scl * a.z); f[3] = (short)f2bf(scl * a.w);
            f[4] = (short)f2bf(scl * b.x); f[5] = (short)f2bf(scl * b.y);
            f[6] = (short)f2bf(scl * b.z); f[7] = (short)f2bf(scl * b.w);
            wfrag[njl][ks] = f;
        }
    }

    float as_[2] = {0.f, 0.f}, aq[2] = {0.f, 0.f};

    // x prefetch: this wave loads ALL 64 rows itself (lanes share via L1 across waves).
    // B-frag[pj]: lane (lr,lg) needs x[16pj+lr][8lg..8lg+7]; lg0: k0-7, lg1: k8-9+ones.
    float2 px[4][4];
    auto PF = [&](int n) {
        const float* xr = x + (size_t)n * 640 + lr * CIN;
        if (lg == 0) {
#pragma unroll
            for (int pj = 0; pj < 4; pj++) {
                const float* r = xr + pj * 160;
                px[pj][0] = *(const float2*)(r + 0); px[pj][1] = *(const float2*)(r + 2);
                px[pj][2] = *(const float2*)(r + 4); px[pj][3] = *(const float2*)(r + 6);
            }
        } else if (lg == 1) {
#pragma unroll
            for (int pj = 0; pj < 4; pj++) px[pj][0] = *(const float2*)(xr + pj * 160 + 8);
        }
    };

    PF(blockIdx.x);

    for (int k = 0; k < NITER; k++) {
        const int n = blockIdx.x + k * NBP;

        // ---- build L0 B-fragments (consume px) ----
        bf16x8 bx[4];
#pragma unroll
        for (int pj = 0; pj < 4; pj++) {
            u32x4 u = {0u, 0u, 0u, 0u};
            if (lg == 0) {
                u[0] = cvtpk(px[pj][0].x, px[pj][0].y); u[1] = cvtpk(px[pj][1].x, px[pj][1].y);
                u[2] = cvtpk(px[pj][2].x, px[pj][2].y); u[3] = cvtpk(px[pj][3].x, px[pj][3].y);
            } else if (lg == 1) {
                u[0] = cvtpk(px[pj][0].x, px[pj][0].y);
                u[1] = 0x00003F80u;       // k10 = 1.0 (shift lane), k11 = 0
            }
            bx[pj] = __builtin_bit_cast(bf16x8, u);
        }
        // ---- issue prefetch for next voxel (hides under the compute below) ----
        if (k < NITER - 1) PF(blockIdx.x + (k + 1) * NBP);

        // ---- L0: 16 MFMA, pack D[ch][p] pairs straight into A-fragments ----
        // azu[pj][ks].u32[q]: mi = 2ks + (q>>1), component q&1 of cvtpk(D)
        u32x4 azu[4][2];
#pragma unroll
        for (int pj = 0; pj < 4; pj++) {
#pragma unroll
            for (int mi = 0; mi < 4; mi++) {
                f32x4 zz = {0.f, 0.f, 0.f, 0.f};
                f32x4 d = __builtin_amdgcn_mfma_f32_16x16x32_bf16(w0f[mi], bx[pj], zz, 0, 0, 0);
                azu[pj][mi >> 1][(mi & 1) * 2]     = cvtpk(d[0], d[1]);
                azu[pj][mi >> 1][(mi & 1) * 2 + 1] = cvtpk(d[2], d[3]);
            }
        }
        // ReLU on packed bf16 (signed i16 max vs 0)
#pragma unroll
        for (int pj = 0; pj < 4; pj++)
#pragma unroll
            for (int ks = 0; ks < 2; ks++)
#pragma unroll
                for (int q = 0; q < 4; q++) azu[pj][ks][q] = pkrelu(azu[pj][ks][q]);

        // ---- agg: max over pj, then 4-stage butterfly over lr (bits 0..3) ----
        u32x4 gu[2];
#pragma unroll
        for (int ks = 0; ks < 2; ks++) {
            gu[ks] = azu[0][ks];
#pragma unroll
            for (int pj = 1; pj < 4; pj++)
#pragma unroll
                for (int q = 0; q < 4; q++) gu[ks][q] = pkmax_u(gu[ks][q], azu[pj][ks][q]);
        }
#pragma unroll
        for (int st = 1; st <= 8; st <<= 1)
#pragma unroll
            for (int ks = 0; ks < 2; ks++)
#pragma unroll
                for (int q = 0; q < 4; q++)
                    gu[ks][q] = pkmax_u(gu[ks][q], __shfl_xor(gu[ks][q], st));
        bf16x8 gf[2] = { __builtin_bit_cast(bf16x8, gu[0]), __builtin_bit_cast(bf16x8, gu[1]) };

        // ---- rep contribution (K 64..127, p-independent), sh1 as C-init ----
        f32x4 dacc[2];
#pragma unroll
        for (int njl = 0; njl < 2; njl++) {
            f32x4 zz = {sh1[njl], sh1[njl], sh1[njl], sh1[njl]};
            zz = __builtin_amdgcn_mfma_f32_16x16x32_bf16(gf[0], wfrag[njl][2], zz, 0, 0, 0);
            dacc[njl] = __builtin_amdgcn_mfma_f32_16x16x32_bf16(gf[1], wfrag[njl][3], zz, 0, 0, 0);
        }

        // ---- main GEMM: own o-cols x all 64 p ----
#pragma unroll
        for (int njl = 0; njl < 2; njl++) {
            float vm = 0.f;
#pragma unroll
            for (int pj = 0; pj < 4; pj++) {
                f32x4 acc = dacc[njl];
                acc = __builtin_amdgcn_mfma_f32_16x16x32_bf16(
                    __builtin_bit_cast(bf16x8, azu[pj][0]), wfrag[njl][0], acc, 0, 0, 0);
                acc = __builtin_amdgcn_mfma_f32_16x16x32_bf16(
                    __builtin_bit_cast(bf16x8, azu[pj][1]), wfrag[njl][1], acc, 0, 0, 0);
                if (STATS) {
#pragma unroll
                    for (int r = 0; r < 4; r++) { as_[njl] += acc[r]; aq[njl] += acc[r] * acc[r]; }
                } else {
#pragma unroll
                    for (int r = 0; r < 4; r++) vm = fmaxf(vm, fmaxf(acc[r], 0.f));
                }
            }
            if (!STATS) {
                vm = fmaxf(vm, __shfl_xor(vm, 16));
                vm = fmaxf(vm, __shfl_xor(vm, 32));
                if (l < 16) pout[(size_t)n * 128 + 32 * w + 16 * njl + l] = vm;
            }
        }
    }

    if (STATS) {
        // per-wave direct partial stores (disjoint cols; no LDS, no sync)
#pragma unroll
        for (int njl = 0; njl < 2; njl++) {
            float s = as_[njl];
            s += __shfl_xor(s, 16); s += __shfl_xor(s, 32);
            float qq = aq[njl];
            qq += __shfl_xor(qq, 16); qq += __shfl_xor(qq, 32);
            if (l < 16) {
                int col = 32 * w + 16 * njl + l;
                pout[(size_t)blockIdx.x * 256 + col] = s;
                pout[(size_t)blockIdx.x * 256 + 128 + col] = qq;
            }
        }
    }
}

extern "C" void kernel_launch(void* const* d_in, const int* in_sizes, int n_in,
                              void* d_out, int out_size, void* d_ws, size_t ws_size,
                              hipStream_t stream) {
    (void)in_sizes; (void)n_in; (void)out_size; (void)ws_size;
    const float* x      = (const float*)d_in[0];
    const float* W0     = (const float*)d_in[1];
    const float* gamma0 = (const float*)d_in[2];
    const float* beta0  = (const float*)d_in[3];
    const float* W1     = (const float*)d_in[4];
    const float* gamma1 = (const float*)d_in[5];
    const float* beta1  = (const float*)d_in[6];
    float* out = (float*)d_out;
    float* ws  = (float*)d_ws;

    k_stats0<<<NB0, 256, 0, stream>>>(x, out);                       // partials -> out
    k_finalize0<<<1, 256, 0, stream>>>(out, ws, W0, gamma0, beta0);
    k_pass<true><<<NBP, 256, 0, stream>>>(x, W0, W1, ws, out);       // partials -> out
    k_finalize1<<<128, 256, 0, stream>>>(out, ws, gamma1, beta1);
    k_pass<false><<<NBP, 256, 0, stream>>>(x, W0, W1, ws, out);      // final output
}

// Round 12
// 237.071 us; speedup vs baseline: 2.3729x; 1.3579x over previous
//
#include <hip/hip_runtime.h>

#define NVOX 20000
#define MPTS 64
#define CIN  10
#define NM   (NVOX*MPTS)      // 1,280,000
#define EPSBN 1e-3f

// ws layout (float offsets); total usage 53 KB (proven safe: R1 used 70 KB)
#define WS_SCALE0 0     // 64
#define WS_SHIFT0 64    // 64
#define WS_SCALE1 128   // 128
#define WS_SHIFT1 256   // 128
#define WS_SH1T   512   // [2][256] floats (FINAL shift table)
#define WS_FTAB   1024  // fragment table: 12 frags x 256 threads x 8 shorts = 48 KB

// d_out doubles as stream-ordered scratch for reduction partials.
#define NB0   1024      // stats0 blocks -> P0 partials [NB0][P0STR]
#define P0STR 72
#define NBP   1250      // k_pass blocks; NITER voxels each, exact
#define NITER 16

typedef short bf16x8 __attribute__((ext_vector_type(8)));
typedef float f32x4  __attribute__((ext_vector_type(4)));
typedef unsigned int u32x4 __attribute__((ext_vector_type(4)));

__device__ __forceinline__ unsigned short f2bf(float f) {
    union { float f; unsigned u; } v; v.f = f;
    unsigned r = v.u + 0x7FFFu + ((v.u >> 16) & 1u);   // RNE to bf16
    return (unsigned short)(r >> 16);
}
// HW packed f32x2 -> bf16x2 (no builtin on gfx950)
__device__ __forceinline__ unsigned cvtpk(float lo, float hi) {
    unsigned d;
    asm("v_cvt_pk_bf16_f32 %0, %1, %2" : "=v"(d) : "v"(lo), "v"(hi));
    return d;
}
// packed u16 max: valid max for ReLU'd (non-negative) bf16 bit patterns
__device__ __forceinline__ unsigned pkmax(unsigned a, unsigned b) {
    unsigned d;
    asm("v_pk_max_u16 %0, %1, %2" : "=v"(d) : "v"(a), "v"(b));
    return d;
}

// x-moment pass: Sx (10) + Sxx (55 packed) via per-block partials, NO atomics.
__global__ __launch_bounds__(256) void k_stats0(const float* __restrict__ x,
                                                float* __restrict__ p0) {
    __shared__ float sm[4][P0STR];
    float sx[CIN];
    float sxx[55];
#pragma unroll
    for (int i = 0; i < CIN; i++) sx[i] = 0.f;
#pragma unroll
    for (int k = 0; k < 55; k++) sxx[k] = 0.f;

    const int t = threadIdx.x;
    const int tid = blockIdx.x * 256 + t;

    for (int g = tid; g < NM / 2; g += NB0 * 256) {
        const float4* xp = (const float4*)(x + (size_t)g * 20);
        float4 a = xp[0], b = xp[1], c = xp[2], d = xp[3], e = xp[4];
        float v0[CIN] = {a.x, a.y, a.z, a.w, b.x, b.y, b.z, b.w, c.x, c.y};
        float v1[CIN] = {c.z, c.w, d.x, d.y, d.z, d.w, e.x, e.y, e.z, e.w};
#pragma unroll
        for (int i = 0; i < CIN; i++) sx[i] += v0[i] + v1[i];
#pragma unroll
        for (int i = 0; i < CIN; i++)
#pragma unroll
            for (int j = 0; j <= i; j++)
                sxx[i * (i + 1) / 2 + j] += v0[i] * v0[j] + v1[i] * v1[j];
    }

    const int l = t & 63, w = t >> 6;
#pragma unroll
    for (int i = 0; i < CIN; i++) {
        float v = sx[i];
#pragma unroll
        for (int off = 32; off; off >>= 1) v += __shfl_xor(v, off, 64);
        if (l == 0) sm[w][i] = v;
    }
#pragma unroll
    for (int k = 0; k < 55; k++) {
        float v = sxx[k];
#pragma unroll
        for (int off = 32; off; off >>= 1) v += __shfl_xor(v, off, 64);
        if (l == 0) sm[w][10 + k] = v;
    }
    __syncthreads();
    if (t < 65)
        p0[blockIdx.x * P0STR + t] = sm[0][t] + sm[1][t] + sm[2][t] + sm[3][t];
}

__global__ void k_finalize0(const float* __restrict__ p0, float* __restrict__ ws,
                            const float* __restrict__ w0,
                            const float* __restrict__ gamma0, const float* __restrict__ beta0) {
    __shared__ float s[P0STR];
    const int t = threadIdx.x;
    if (t < 65) {
        float acc = 0.f;
#pragma unroll 8
        for (int r = 0; r < NB0; r++) acc += p0[r * P0STR + t];
        s[t] = acc;
    }
    __syncthreads();
    if (t < 64) {
        float w[CIN];
#pragma unroll
        for (int i = 0; i < CIN; i++) w[i] = w0[t * CIN + i];
        float m = 0.f;
#pragma unroll
        for (int i = 0; i < CIN; i++) m += w[i] * s[i];
        m *= (1.f / NM);
        float q = 0.f;
#pragma unroll
        for (int i = 0; i < CIN; i++)
#pragma unroll
            for (int j = 0; j <= i; j++)
                q += ((i == j) ? 1.f : 2.f) * w[i] * w[j] * s[10 + i * (i + 1) / 2 + j];
        q *= (1.f / NM);
        float var = q - m * m;
        float scale = gamma0[t] * rsqrtf(var + EPSBN);
        ws[WS_SCALE0 + t] = scale;
        ws[WS_SHIFT0 + t] = beta0[t] - m * scale;
    }
}

__global__ void k_finalize1(const float* __restrict__ p1, float* __restrict__ ws,
                            const float* __restrict__ gamma1, const float* __restrict__ beta1) {
    __shared__ float sm[2][4];
    const int c = blockIdx.x;
    const int t = threadIdx.x, l = t & 63, w = t >> 6;
    float s = 0.f, qq = 0.f;
    for (int r = t; r < NBP; r += 256) {
        s  += p1[(size_t)r * 256 + c];
        qq += p1[(size_t)r * 256 + 128 + c];
    }
#pragma unroll
    for (int off = 32; off; off >>= 1) { s += __shfl_xor(s, off, 64); qq += __shfl_xor(qq, off, 64); }
    if (l == 0) { sm[0][w] = s; sm[1][w] = qq; }
    __syncthreads();
    if (t == 0) {
        float S = sm[0][0] + sm[0][1] + sm[0][2] + sm[0][3];
        float Q = sm[1][0] + sm[1][1] + sm[1][2] + sm[1][3];
        float m = S * (1.f / NM);
        float var = Q * (1.f / NM) - m * m;
        float scale = gamma1[c] * rsqrtf(var + EPSBN);
        ws[WS_SCALE1 + c] = scale;
        ws[WS_SHIFT1 + c] = beta1[c] - m * scale;
    }
}

// Fragment-table prep (1 block x 256 threads). Re-run every call (graph-replay safe).
// frag index f: 0..3 = w0f[mi] (BN0 folded); 4..11 = wfrag[njl*4+ks].
// scaled=0 (before STATS pass): raw W1.  scaled=1 (before FINAL): W1*sc1, + SH1T table.
// Table layout [f][t][8 shorts] -> k_pass load of frag f is a fully coalesced dwordx4.
__global__ void k_prep(const float* __restrict__ w0, const float* __restrict__ w1,
                       float* __restrict__ ws, int scaled) {
    const int t = threadIdx.x;
    const int l = t & 63, w = t >> 6, lr = l & 15, lg = l >> 4;
    unsigned short* ftab = (unsigned short*)(ws + WS_FTAB);

#pragma unroll
    for (int mi = 0; mi < 4; mi++) {
        int ch = 16 * mi + lr;
        float sc = ws[WS_SCALE0 + ch], sh = ws[WS_SHIFT0 + ch];
        bf16x8 f;
#pragma unroll
        for (int j = 0; j < 8; j++) {
            int k = 8 * lg + j;
            float v = (k < CIN) ? sc * w0[ch * CIN + k] : (k == CIN ? sh : 0.f);
            f[j] = (short)f2bf(v);
        }
        *(bf16x8*)&ftab[(mi * 256 + t) * 8] = f;
    }
#pragma unroll
    for (int njl = 0; njl < 2; njl++) {
        int col = 32 * w + 16 * njl + lr;
        float scl = scaled ? ws[WS_SCALE1 + col] : 1.f;
        if (scaled) ws[WS_SH1T + njl * 256 + t] = ws[WS_SHIFT1 + col];
        const float* wrow = w1 + col * 128;
#pragma unroll
        for (int ks = 0; ks < 4; ks++) {
            float4 a = *(const float4*)(wrow + 32 * ks + 8 * lg);
            float4 b = *(const float4*)(wrow + 32 * ks + 8 * lg + 4);
            bf16x8 f;
            f[0] = (short)f2bf(scl * a.x); f[1] = (short)f2bf(scl * a.y);
            f[2] = (short)f2bf(scl * a.z); f[3] = (short)f2bf(scl * a.w);
            f[4] = (short)f2bf(scl * b.x); f[5] = (short)f2bf(scl * b.y);
            f[6] = (short)f2bf(scl * b.z); f[7] = (short)f2bf(scl * b.w);
            *(bf16x8*)&ftab[((4 + njl * 4 + ks) * 256 + t) * 8] = f;
        }
    }
}

// R5-proven k_pass (220.9 us structure, byte-identical pipeline) with:
//  - fragment setup from precomputed table (12 coalesced dwordx4 + 2 scalar loads)
//  - NITER 16 (setup amortized 16 voxels/block; 1250 blocks = 4.9/CU)
// zB [p][ch] stride 72 shorts (144 B = 9x16B slots -> natural per-row slot rotation,
// conflict-free per 8-lane beat). zB writes + AGG readback are wave-private (in-order
// DS per wave); cross-wave bz/gfrag reads only after the barrier. BN1 folded: wfrag
// pre-scaled by sc1 (FINAL table), sh1 injected as the dacc C-init (exact, verified R9).
template <bool STATS>
__global__ __launch_bounds__(256) void k_pass(const float* __restrict__ x,
                                              const float* __restrict__ ws,
                                              float* __restrict__ pout) {
    __shared__ unsigned short zB[MPTS * 72];   // 9216 B  [p][ch]
    __shared__ unsigned short aggP[4 * 64];    // 512 B
    __shared__ float pbuf[256];                // 1024 B (STATS staging)

    const int t  = threadIdx.x;
    const int l  = t & 63;
    const int w  = t >> 6;
    const int lr = l & 15;
    const int lg = l >> 4;
    const int prow = 16 * w + lr;              // this lane's point row (produce)

    // ---- fragment setup from table ----
    const unsigned short* ftab = (const unsigned short*)(ws + WS_FTAB);
    bf16x8 w0f[4];
#pragma unroll
    for (int mi = 0; mi < 4; mi++)
        w0f[mi] = *(const bf16x8*)&ftab[(mi * 256 + t) * 8];
    bf16x8 wfrag[2][4];
#pragma unroll
    for (int njl = 0; njl < 2; njl++)
#pragma unroll
        for (int ks = 0; ks < 4; ks++)
            wfrag[njl][ks] = *(const bf16x8*)&ftab[((4 + njl * 4 + ks) * 256 + t) * 8];
    float sh1[2] = {0.f, 0.f};
    if constexpr (!STATS) {
        sh1[0] = ws[WS_SH1T + t];
        sh1[1] = ws[WS_SH1T + 256 + t];
    }

    float as_[2] = {0.f, 0.f}, aq[2] = {0.f, 0.f};

    float2 pfA, pfB, pfC, pfD;
    auto PF = [&](int n) {
        const float* xr = x + (size_t)n * 640 + prow * CIN;
        if (lg == 0) {
            pfA = *(const float2*)(xr + 0); pfB = *(const float2*)(xr + 2);
            pfC = *(const float2*)(xr + 4); pfD = *(const float2*)(xr + 6);
        } else if (lg == 1) {
            pfA = *(const float2*)(xr + 8);
        }
    };
    auto MKBX = [&]() -> bf16x8 {
        u32x4 u = {0u, 0u, 0u, 0u};
        if (lg == 0) {
            u[0] = cvtpk(pfA.x, pfA.y); u[1] = cvtpk(pfB.x, pfB.y);
            u[2] = cvtpk(pfC.x, pfC.y); u[3] = cvtpk(pfD.x, pfD.y);
        } else if (lg == 1) {
            u[0] = cvtpk(pfA.x, pfA.y);
            u[1] = 0x00003F80u;       // k10 = 1.0 (shift lane), k11 = 0
        }
        return __builtin_bit_cast(bf16x8, u);
    };

    PF(blockIdx.x);

    for (int k = 0; k < NITER; k++) {
        const int n = blockIdx.x + k * NBP;

        bf16x8 bx = MKBX();
        if (k < NITER - 1) PF(blockIdx.x + (k + 1) * NBP);

        // ---- L0: 4 MFMA + ReLU + packed zB write (rows prow = wave-own) ----
#pragma unroll
        for (int mi = 0; mi < 4; mi++) {
            f32x4 zz = {0.f, 0.f, 0.f, 0.f};
            f32x4 a0 = __builtin_amdgcn_mfma_f32_16x16x32_bf16(w0f[mi], bx, zz, 0, 0, 0);
            uint2 dd = { cvtpk(fmaxf(a0[0], 0.f), fmaxf(a0[1], 0.f)),
                         cvtpk(fmaxf(a0[2], 0.f), fmaxf(a0[3], 0.f)) };
            *(uint2*)&zB[prow * 72 + 16 * mi + 4 * lg] = dd;   // ch 16mi+4lg..+3
        }

        // ---- agg partials: wave-local max over own 16 zB rows (DS in-order per wave) ----
        {
            int cs = l & 7;
            int pa = 16 * w + 2 * (l >> 3);
            u32x4 ra = *(const u32x4*)&zB[pa * 72 + cs * 8];
            u32x4 rb = *(const u32x4*)&zB[(pa + 1) * 72 + cs * 8];
            u32x4 m;
#pragma unroll
            for (int k2 = 0; k2 < 4; k2++) m[k2] = pkmax(ra[k2], rb[k2]);
#pragma unroll
            for (int off = 8; off <= 32; off <<= 1)
#pragma unroll
                for (int k2 = 0; k2 < 4; k2++) m[k2] = pkmax(m[k2], __shfl_xor(m[k2], off));
            if (l < 8) *(u32x4*)&aggP[w * 64 + l * 8] = m;
        }

        asm volatile("s_waitcnt lgkmcnt(0)" ::: "memory");
        __builtin_amdgcn_s_barrier();          // B_a: zB + aggP globally ready

        // ---- layer-1 fragments ----
        bf16x8 bz[4][2];
#pragma unroll
        for (int pj = 0; pj < 4; pj++) {
            int p = 16 * pj + lr;
#pragma unroll
            for (int ks = 0; ks < 2; ks++)
                bz[pj][ks] = *(const bf16x8*)&zB[p * 72 + (4 * ks + lg) * 8];
        }
        bf16x8 gf[2];
#pragma unroll
        for (int ks = 0; ks < 2; ks++) {
            int sl = (4 * ks + lg) * 8;
            u32x4 g = *(const u32x4*)&aggP[sl];
#pragma unroll
            for (int wv = 1; wv < 4; wv++) {
                u32x4 h2 = *(const u32x4*)&aggP[wv * 64 + sl];
#pragma unroll
                for (int k2 = 0; k2 < 4; k2++) g[k2] = pkmax(g[k2], h2[k2]);
            }
            gf[ks] = __builtin_bit_cast(bf16x8, g);
        }

        asm volatile("s_waitcnt lgkmcnt(0)" ::: "memory");
        __builtin_amdgcn_s_barrier();          // B_b: fragments landed; zB/aggP free

        // ---- layer-1 GEMM (sh1 as C-init; wfrag pre-scaled for FINAL) ----
        f32x4 dacc[2];
#pragma unroll
        for (int njl = 0; njl < 2; njl++) {
            f32x4 zz = {sh1[njl], sh1[njl], sh1[njl], sh1[njl]};
            zz = __builtin_amdgcn_mfma_f32_16x16x32_bf16(gf[0], wfrag[njl][2], zz, 0, 0, 0);
            dacc[njl] = __builtin_amdgcn_mfma_f32_16x16x32_bf16(gf[1], wfrag[njl][3], zz, 0, 0, 0);
        }

#pragma unroll
        for (int njl = 0; njl < 2; njl++) {
            float vm = 0.f;
#pragma unroll
            for (int mi = 0; mi < 4; mi++) {
                f32x4 acc = dacc[njl];
                acc = __builtin_amdgcn_mfma_f32_16x16x32_bf16(bz[mi][0], wfrag[njl][0], acc, 0, 0, 0);
                acc = __builtin_amdgcn_mfma_f32_16x16x32_bf16(bz[mi][1], wfrag[njl][1], acc, 0, 0, 0);
                if (STATS) {
#pragma unroll
                    for (int r = 0; r < 4; r++) { as_[njl] += acc[r]; aq[njl] += acc[r] * acc[r]; }
                } else {
#pragma unroll
                    for (int r = 0; r < 4; r++) vm = fmaxf(vm, fmaxf(acc[r], 0.f));
                }
            }
            if (!STATS) {
                vm = fmaxf(vm, __shfl_xor(vm, 16));
                vm = fmaxf(vm, __shfl_xor(vm, 32));
                if (l < 16) pout[(size_t)n * 128 + 32 * w + 16 * njl + l] = vm;
            }
        }
    }

    if (STATS) {
        // disjoint cols across waves -> single staging array, one coalesced store
#pragma unroll
        for (int njl = 0; njl < 2; njl++) {
            float s = as_[njl];
            s += __shfl_xor(s, 16); s += __shfl_xor(s, 32);
            float qq = aq[njl];
            qq += __shfl_xor(qq, 16); qq += __shfl_xor(qq, 32);
            if (l < 16) {
                int col = 32 * w + 16 * njl + l;
                pbuf[col] = s;
                pbuf[128 + col] = qq;
            }
        }
        __syncthreads();
        pout[(size_t)blockIdx.x * 256 + t] = pbuf[t];
    }
}

extern "C" void kernel_launch(void* const* d_in, const int* in_sizes, int n_in,
                              void* d_out, int out_size, void* d_ws, size_t ws_size,
                              hipStream_t stream) {
    (void)in_sizes; (void)n_in; (void)out_size; (void)ws_size;
    const float* x      = (const float*)d_in[0];
    const float* W0     = (const float*)d_in[1];
    const float* gamma0 = (const float*)d_in[2];
    const float* beta0  = (const float*)d_in[3];
    const float* W1     = (const float*)d_in[4];
    const float* gamma1 = (const float*)d_in[5];
    const float* beta1  = (const float*)d_in[6];
    float* out = (float*)d_out;
    float* ws  = (float*)d_ws;

    k_stats0<<<NB0, 256, 0, stream>>>(x, out);                        // partials -> out
    k_finalize0<<<1, 256, 0, stream>>>(out, ws, W0, gamma0, beta0);
    k_prep<<<1, 256, 0, stream>>>(W0, W1, ws, 0);                     // unscaled table
    k_pass<true><<<NBP, 256, 0, stream>>>(x, ws, out);                // partials -> out
    k_finalize1<<<128, 256, 0, stream>>>(out, ws, gamma1, beta1);
    k_prep<<<1, 256, 0, stream>>>(W0, W1, ws, 1);                     // scaled table + sh1
    k_pass<false><<<NBP, 256, 0, stream>>>(x, ws, out);               // final output
}